// Round 12
// baseline (76.587 us; speedup 1.0000x reference)
//
#include <hip/hip_runtime.h>
#include <hip/hip_bf16.h>
#include <math.h>

typedef unsigned short u16;
typedef unsigned int   u32;
typedef __attribute__((ext_vector_type(8))) short short8;
typedef __attribute__((ext_vector_type(4))) float f32x4;

// Problem constants
#define B_  4
#define C_  64
#define H_  128
#define W_  128
#define O_  64
#define HW_ (H_ * W_)

__device__ __forceinline__ u16 f2bf(float f) {
    __hip_bfloat16 h = __float2bfloat16(f);
    u16 u; __builtin_memcpy(&u, &h, 2); return u;
}
__device__ __forceinline__ float bf2f(u16 u) {
    return __uint_as_float((u32)u << 16);
}
__device__ __forceinline__ u32 pkbf(float lo, float hi) {
    return ((u32)f2bf(hi) << 16) | (u32)f2bf(lo);
}
__device__ __forceinline__ float bflo(u32 v) { return __uint_as_float(v << 16); }
__device__ __forceinline__ float bfhi(u32 v) { return __uint_as_float(v & 0xffff0000u); }

// -------------------------------------------------------------------------
// prep: blocks 0..1023   : transpose x (B,C,H,W) f32 -> xt (B,H,W,C) bf16
//       blocks 1024..1239: repack weight->Wb, ow|mw->OWb (A-frag order)
// K index convention: kidx = tap*64 + c  (tap-major, channel minor)
// A-frag (16x16x32): lane l holds A[o = l&15][k = ks*32 + (l>>4)*8 + j]
// -------------------------------------------------------------------------
__global__ __launch_bounds__(256) void prep(
    const float* __restrict__ x, const float* __restrict__ weight,
    const float* __restrict__ ow, const float* __restrict__ mw,
    u16* __restrict__ xt, u16* __restrict__ Wb, u16* __restrict__ OWb)
{
    int i = blockIdx.x, t = threadIdx.x;
    if (i < 1024) {                             // transpose
        __shared__ float tile[64][65];
        int lb = i >> 8;                        // 0..3
        int pix0 = (i & 255) << 6;
        const float* xb = x + ((size_t)lb << 20);
#pragma unroll
        for (int it = 0; it < 16; ++it) {
            int e = it * 256 + t;
            int c = e >> 6, pl = e & 63;
            tile[c][pl] = xb[((size_t)c << 14) + pix0 + pl];
        }
        __syncthreads();
        u16* xo = xt + ((((size_t)lb << 14) + pix0) << 6);
#pragma unroll
        for (int it = 0; it < 16; ++it) {
            int e = it * 256 + t;
            int c = e & 63, pl = e >> 6;
            xo[((size_t)pl << 6) + c] = f2bf(tile[c][pl]);
        }
    } else {
        int e = (i - 1024) * 256 + t;           // 0..55295
        if (e < 36864) {                        // Wb
            int j = e & 7, ln = (e >> 3) & 63;
            int ks = (e >> 9) % 18, ot = e / 9216;
            int o = ot * 16 + (ln & 15);
            int kidx = ks * 32 + ((ln >> 4) << 3) + j;
            int k = kidx >> 6, c = kidx & 63;
            Wb[e] = f2bf(weight[((size_t)(o * 64 + c)) * 9 + k]);
        } else {                                // OWb
            int e2 = e - 36864;
            int j = e2 & 7, ln = (e2 >> 3) & 63;
            int ks = (e2 >> 9) % 18, ot = e2 / 9216;
            int o = ot * 16 + (ln & 15);
            int kidx = ks * 32 + ((ln >> 4) << 3) + j;
            int k = kidx >> 6, c = kidx & 63;
            float v = 0.0f;
            if (o < 18)      v = ow[((size_t)(o * 64 + c)) * 9 + k];
            else if (o < 27) v = mw[((size_t)((o - 18) * 64 + c)) * 9 + k];
            OWb[e2] = f2bf(v);
        }
    }
}

// -------------------------------------------------------------------------
// fused_dcn: round-6 phase structure, widened. Block = 16 pixels (one row
// segment), 4 waves. Phases (3 barriers):
//   K1 : wave = (otile, khalf): 9 batched global im2col loads -> 9 MFMAs
//        (offset/mask conv, K=576 split in two 288-halves) -> kp partials
//   P1 : threads 0..143: sum kp halves + bias/sigmoid, bilinear corner
//        byte-offsets (int4) + bf16 weights -> pwp/pww LDS
//   P2 : deformable gather, 1152 INDEPENDENT units (tap,pix,ch-octet):
//        4 x dwordx4 corner loads, 8-ch interp, 1 swizzled ds_write_b128
//        -> S[16][576] (bf16 B-operand, XOR-swizzled)
//   P3 : wave = otile: 18 x {swizzled ds_read_b128 + A-frag + MFMA} -> out
// LDS: S (18432, kp overlaid in first 4KB) + pwp 4608 + pww 1152 = 24192 B
// -> 6 blocks/CU. Grid 4096 blocks = 16384 waves.
// -------------------------------------------------------------------------
__global__ __launch_bounds__(256, 6) void fused_dcn(
    const u16* __restrict__ xt,
    const u16* __restrict__ Wb, const u16* __restrict__ OWb,
    const float* __restrict__ ob, const float* __restrict__ mb,
    float* __restrict__ out)
{
    __shared__ __align__(16) char lds_a[16][1152];  // S[16][576] u16; kp f32[1024] overlay
    __shared__ __align__(16) int4    pwp[144];      // corner byte offsets
    __shared__ __align__(16) ushort4 pww[144];      // bf16 bilinear*mask weights

    u16 (*S)[576] = (u16(*)[576])lds_a;
    float* kpf = (float*)lds_a;     // [kh*2+ot][row 0..15][pix 0..15]

    const int t = threadIdx.x;
    const int lane = t & 63;
    const int wv = t >> 6;          // 0..3
    const int mypix = lane & 15;
    const int hi = lane >> 4;       // channel octet (within a 32-ch half for K1)

    int bid0 = blockIdx.x;          // 4096 blocks
    const int bid = (bid0 & 7) * 512 + (bid0 >> 3);   // XCD swizzle (bijective)
    const int lb = bid >> 10;       // batch
    const int pix0 = (bid & 1023) << 4;
    const int h  = pix0 >> 7;       // 16 pixels share one row
    const int w0 = pix0 & 127;

    const u16* xtb = xt + ((size_t)lb << 20);

    // ---- K1: offset/mask conv; wave = (otile, K-half); batched loads ----
    {
        const int ot = wv & 1, kh = wv >> 1;
        f32x4 k1 = {0.f, 0.f, 0.f, 0.f};
        uint4 raw[9];
#pragma unroll
        for (int q = 0; q < 9; ++q) {
            int ks = kh * 9 + q;
            int tap = ks >> 1;
            int ky = tap / 3, kx = tap % 3;
            int y  = h - 1 + ky;
            int xx = w0 + mypix - 1 + kx;
            int idx = ((y & 127) << 7) + (xx & 127);    // wrapped -> safe
            raw[q] = *(const uint4*)(xtb + ((size_t)idx << 6) + ((ks & 1) << 5) + (hi << 3));
        }
        __builtin_amdgcn_sched_barrier(0);
#pragma unroll
        for (int q = 0; q < 9; ++q) {
            int ks = kh * 9 + q;
            int tap = ks >> 1;
            int ky = tap / 3, kx = tap % 3;
            int y  = h - 1 + ky;
            int xx = w0 + mypix - 1 + kx;
            bool valid = ((unsigned)y < (unsigned)H_) && ((unsigned)xx < (unsigned)W_);
            uint4 rw = raw[q];
            rw.x = valid ? rw.x : 0u;
            rw.y = valid ? rw.y : 0u;
            rw.z = valid ? rw.z : 0u;
            rw.w = valid ? rw.w : 0u;
            short8 bfr;
            __builtin_memcpy(&bfr, &rw, 16);
            short8 wa = ((const short8*)OWb)[(ot * 18 + ks) * 64 + lane];
            k1 = __builtin_amdgcn_mfma_f32_16x16x32_bf16(wa, bfr, k1, 0, 0, 0);
        }
        // kp partial: [kh*2+ot][hi*4+r][mypix]
#pragma unroll
        for (int r = 0; r < 4; ++r)
            kpf[((kh << 1) + ot) * 256 + ((hi << 2) + r) * 16 + mypix] = k1[r];
    }
    __syncthreads();

    // ---- P1: combine K-halves + bias, sigmoid, bilinear params ----
    if (t < 144) {
        int tap = t >> 4, pix = t & 15;
        int ky = tap / 3, kx = tap % 3;
        int ocy = 2 * tap, ocx = 2 * tap + 1, ocm = 18 + tap;
        float dy = kpf[((ocy >> 4)) * 256 + (ocy & 15) * 16 + pix]
                 + kpf[512 + ((ocy >> 4)) * 256 + (ocy & 15) * 16 + pix] + ob[ocy];
        float dx = kpf[((ocx >> 4)) * 256 + (ocx & 15) * 16 + pix]
                 + kpf[512 + ((ocx >> 4)) * 256 + (ocx & 15) * 16 + pix] + ob[ocx];
        float sm = kpf[256 + (ocm - 16) * 16 + pix]
                 + kpf[512 + 256 + (ocm - 16) * 16 + pix] + mb[tap];
        float m  = 2.0f / (1.0f + __expf(-sm));
        float py = (float)(h - 1 + ky) + dy;
        float px = (float)(w0 + pix - 1 + kx) + dx;
        float y0f = floorf(py), x0f = floorf(px);
        float fy = py - y0f, fx = px - x0f;
        int y0 = (int)y0f, x0 = (int)x0f;
        int y1 = y0 + 1, x1 = x0 + 1;
        bool vy0 = (unsigned)y0 < (unsigned)H_;
        bool vy1 = (unsigned)y1 < (unsigned)H_;
        bool vx0 = (unsigned)x0 < (unsigned)W_;
        bool vx1 = (unsigned)x1 < (unsigned)W_;
        float w00 = (1.f - fy) * (1.f - fx) * m; if (!(vy0 && vx0)) w00 = 0.f;
        float w01 = (1.f - fy) * fx          * m; if (!(vy0 && vx1)) w01 = 0.f;
        float w10 = fy * (1.f - fx)          * m; if (!(vy1 && vx0)) w10 = 0.f;
        float w11 = fy * fx                   * m; if (!(vy1 && vx1)) w11 = 0.f;
        int y0c = min(max(y0, 0), H_ - 1);
        int y1c = min(max(y1, 0), H_ - 1);
        int x0c = min(max(x0, 0), W_ - 1);
        int x1c = min(max(x1, 0), W_ - 1);
        // byte offsets into xt batch slab: pos (elem) * 64ch * 2B = pos<<7
        pwp[t] = make_int4(((y0c << 7) + x0c) << 7, ((y0c << 7) + x1c) << 7,
                           ((y1c << 7) + x0c) << 7, ((y1c << 7) + x1c) << 7);
        pww[t] = make_ushort4(f2bf(w00), f2bf(w01), f2bf(w10), f2bf(w11));
    }
    __syncthreads();

    // ---- P2: deformable gather, 1152 independent (tap,pix,octet) units ----
    {
        const char* xb8 = (const char*)xtb;
#pragma unroll
        for (int i = 0; i < 5; ++i) {
            int u = i * 256 + t;
            if (u < 1152) {
                int tap = u >> 7, oct = (u >> 4) & 7, pix = u & 15;
                int4    ofs = pwp[tap * 16 + pix];
                ushort4 wq  = pww[tap * 16 + pix];
                float wtx = bf2f(wq.x), wty = bf2f(wq.y);
                float wtz = bf2f(wq.z), wtw = bf2f(wq.w);
                int co = oct << 4;
                uint4 r00 = *(const uint4*)(xb8 + ofs.x + co);
                uint4 r01 = *(const uint4*)(xb8 + ofs.y + co);
                uint4 r10 = *(const uint4*)(xb8 + ofs.z + co);
                uint4 r11 = *(const uint4*)(xb8 + ofs.w + co);
                const u32* q00 = (const u32*)&r00;
                const u32* q01 = (const u32*)&r01;
                const u32* q10 = (const u32*)&r10;
                const u32* q11 = (const u32*)&r11;
                u32 bw[4];
#pragma unroll
                for (int q = 0; q < 4; ++q) {
                    float slo = bflo(q00[q]) * wtx;
                    slo = fmaf(bflo(q01[q]), wty, slo);
                    slo = fmaf(bflo(q10[q]), wtz, slo);
                    slo = fmaf(bflo(q11[q]), wtw, slo);
                    float shi = bfhi(q00[q]) * wtx;
                    shi = fmaf(bfhi(q01[q]), wty, shi);
                    shi = fmaf(bfhi(q10[q]), wtz, shi);
                    shi = fmaf(bfhi(q11[q]), wtw, shi);
                    bw[q] = pkbf(slo, shi);
                }
                // swizzled store: channels oct*8..+8 at u16-col (oct^(pix&7))*8
                int col = tap * 64 + ((oct ^ (pix & 7)) << 3);
                uint4 v; __builtin_memcpy(&v, bw, 16);
                *(uint4*)&S[pix][col] = v;
            }
        }
    }
    __syncthreads();

    // ---- P3: main contraction, wave = otile, M=64 x N=16 x K=576 ----
    {
        f32x4 acc = {0.f, 0.f, 0.f, 0.f};
        const int brow = mypix;
        const int swz = (brow & 7) << 3;
#pragma unroll
        for (int ks = 0; ks < 18; ++ks) {
            int coff = ((ks & 1) << 5) + (hi << 3);
            short8 bfr = *(const short8*)&S[brow][(ks >> 1) * 64 + (coff ^ swz)];
            short8 a = ((const short8*)Wb)[(wv * 18 + ks) * 64 + lane];
            acc = __builtin_amdgcn_mfma_f32_16x16x32_bf16(a, bfr, acc, 0, 0, 0);
        }
        float* op = out + ((size_t)lb << 20) + pix0;
#pragma unroll
        for (int r = 0; r < 4; ++r) {
            int o = wv * 16 + (hi << 2) + r;
            op[((size_t)o << 14) + brow] = acc[r];
        }
    }
}

// -------------------------------------------------------------------------
extern "C" void kernel_launch(void* const* d_in, const int* in_sizes, int n_in,
                              void* d_out, int out_size, void* d_ws, size_t ws_size,
                              hipStream_t stream)
{
    const float* x        = (const float*)d_in[0];
    const float* offset_w = (const float*)d_in[1];
    const float* offset_b = (const float*)d_in[2];
    const float* mod_w    = (const float*)d_in[3];
    const float* mod_b    = (const float*)d_in[4];
    const float* weight   = (const float*)d_in[5];
    float* out = (float*)d_out;

    // Workspace (u16), total ~8.1 MiB:
    //   Wb : 36864 | OWb : 18432 | xt : 4 batches * HW * C = 4,194,304
    u16* Wb  = (u16*)d_ws;
    u16* OWb = Wb + 36864;
    u16* xt  = OWb + 18432;

    prep<<<1240, 256, 0, stream>>>(x, weight, offset_w, mod_w, xt, Wb, OWb);
    fused_dcn<<<4096, 256, 0, stream>>>(xt, Wb, OWb, offset_b, mod_b, out);
}

// Round 13
// 51.676 us; speedup vs baseline: 1.4821x; 1.4821x over previous
//
#include <hip/hip_runtime.h>
#include <hip/hip_bf16.h>
#include <math.h>

typedef unsigned short u16;
typedef unsigned int   u32;
typedef __attribute__((ext_vector_type(8))) short short8;
typedef __attribute__((ext_vector_type(4))) float f32x4;

// Problem constants
#define B_  4
#define C_  64
#define H_  128
#define W_  128
#define O_  64
#define HW_ (H_ * W_)

__device__ __forceinline__ u16 f2bf(float f) {
    __hip_bfloat16 h = __float2bfloat16(f);
    u16 u; __builtin_memcpy(&u, &h, 2); return u;
}
__device__ __forceinline__ float bf2f(u16 u) {
    return __uint_as_float((u32)u << 16);
}
__device__ __forceinline__ u32 pkbf(float lo, float hi) {
    return ((u32)f2bf(hi) << 16) | (u32)f2bf(lo);
}
__device__ __forceinline__ float bflo(u32 v) { return __uint_as_float(v << 16); }
__device__ __forceinline__ float bfhi(u32 v) { return __uint_as_float(v & 0xffff0000u); }

// -------------------------------------------------------------------------
// prep: blocks 0..1023   : transpose x (B,C,H,W) f32 -> xt (B,H,W,C) bf16
//       blocks 1024..1239: repack weight->Wb, ow|mw->OWb (A-frag order)
// K index convention: kidx = tap*64 + c  (tap-major, channel minor)
// A-frag (16x16x32): lane l holds A[o = l&15][k = ks*32 + (l>>4)*8 + j]
// -------------------------------------------------------------------------
__global__ __launch_bounds__(256) void prep(
    const float* __restrict__ x, const float* __restrict__ weight,
    const float* __restrict__ ow, const float* __restrict__ mw,
    u16* __restrict__ xt, u16* __restrict__ Wb, u16* __restrict__ OWb)
{
    int i = blockIdx.x, t = threadIdx.x;
    if (i < 1024) {                             // transpose
        __shared__ float tile[64][65];
        int lb = i >> 8;                        // 0..3
        int pix0 = (i & 255) << 6;
        const float* xb = x + ((size_t)lb << 20);
#pragma unroll
        for (int it = 0; it < 16; ++it) {
            int e = it * 256 + t;
            int c = e >> 6, pl = e & 63;
            tile[c][pl] = xb[((size_t)c << 14) + pix0 + pl];
        }
        __syncthreads();
        u16* xo = xt + ((((size_t)lb << 14) + pix0) << 6);
#pragma unroll
        for (int it = 0; it < 16; ++it) {
            int e = it * 256 + t;
            int c = e & 63, pl = e >> 6;
            xo[((size_t)pl << 6) + c] = f2bf(tile[c][pl]);
        }
    } else {
        int e = (i - 1024) * 256 + t;           // 0..55295
        if (e < 36864) {                        // Wb
            int j = e & 7, ln = (e >> 3) & 63;
            int ks = (e >> 9) % 18, ot = e / 9216;
            int o = ot * 16 + (ln & 15);
            int kidx = ks * 32 + ((ln >> 4) << 3) + j;
            int k = kidx >> 6, c = kidx & 63;
            Wb[e] = f2bf(weight[((size_t)(o * 64 + c)) * 9 + k]);
        } else {                                // OWb
            int e2 = e - 36864;
            int j = e2 & 7, ln = (e2 >> 3) & 63;
            int ks = (e2 >> 9) % 18, ot = e2 / 9216;
            int o = ot * 16 + (ln & 15);
            int kidx = ks * 32 + ((ln >> 4) << 3) + j;
            int k = kidx >> 6, c = kidx & 63;
            float v = 0.0f;
            if (o < 18)      v = ow[((size_t)(o * 64 + c)) * 9 + k];
            else if (o < 27) v = mw[((size_t)((o - 18) * 64 + c)) * 9 + k];
            OWb[e2] = f2bf(v);
        }
    }
}

// -------------------------------------------------------------------------
// fused_dcn: round-6 structure (verified 53.7 us, VALU 64%) with width
// upgrades that PRESERVE its coalesced lane->address patterns.
// Block = 16 pixels (one row segment), 4 waves, 4 barriers:
//   P0 : im2col staging, uint4/lane, oct-fastest (8 consecutive pixels per
//        wave-load, 1KB contiguous) -> S[16][576] group-XOR swizzled
//   K1 : waves 0,1 (= otile): 18 swizzled ds_read_b128 + 18 MFMA
//        -> param[27][16] (offset/mask conv)
//   st1: threads 0..143: bilinear corner byte-offsets (int4) + bf16 wts
//   P2 : deformable gather, uint2/lane (4ch), slot-fastest (16 lanes cover
//        one full 128B corner-row; 4 rows/load) -> rebuild S swizzled
//   P3 : wave = otile: 18 swizzled ds_read_b128 + A-frags + MFMA -> out
// LDS: 18432 + 1728 + 2304 + 1152 = 23616 B -> 6 blocks/CU.
// -------------------------------------------------------------------------
__global__ __launch_bounds__(256, 6) void fused_dcn(
    const u16* __restrict__ xt,
    const u16* __restrict__ Wb, const u16* __restrict__ OWb,
    const float* __restrict__ ob, const float* __restrict__ mb,
    float* __restrict__ out)
{
    __shared__ __align__(16) u16 S[16][576];     // 18432 B, group-XOR swizzled
    __shared__ float   param[27][16];            //  1728 B
    __shared__ __align__(16) int4    pwp[144];   //  2304 B corner byte offsets
    __shared__ __align__(16) ushort4 pww[144];   //  1152 B bf16 bilinear*mask wts

    const int t = threadIdx.x;
    const int lane = t & 63;
    const int wv = t >> 6;          // 0..3

    int bid0 = blockIdx.x;          // 4096 blocks
    const int bid = (bid0 & 7) * 512 + (bid0 >> 3);   // XCD swizzle (bijective)
    const int lb = bid >> 10;       // batch
    const int pix0 = (bid & 1023) << 4;
    const int h  = pix0 >> 7;       // 16 pixels share one row
    const int w0 = pix0 & 127;

    const u16* xtb = xt + ((size_t)lb << 20);
    const char* xb8 = (const char*)xtb;

    // ---- P0: im2col staging, uint4/lane, 1152 tasks (144 units x 8 octs) ----
    // unit u = tap*16 + pixl; lane map: oct fastest -> 8 consecutive pixels
    // per wave-load, same tap -> contiguous 1KB global read.
#pragma unroll
    for (int i = 0; i < 4; ++i) {
        int e = i * 256 + t;
        int u = e >> 3, oct = e & 7;
        int k = u >> 4, pixl = u & 15;
        int ky = k / 3, kx = k - 3 * ky;
        int y = h - 1 + ky, xx = w0 + pixl - 1 + kx;
        bool valid = ((unsigned)y < 128u) && ((unsigned)xx < 128u);
        int idx = ((y & 127) << 7) + (xx & 127);
        uint4 v = *(const uint4*)(xtb + ((size_t)idx << 6) + (oct << 3));
        v.x = valid ? v.x : 0u;
        v.y = valid ? v.y : 0u;
        v.z = valid ? v.z : 0u;
        v.w = valid ? v.w : 0u;
        *(uint4*)&S[pixl][k * 64 + ((oct ^ (pixl & 7)) << 3)] = v;
    }
    if (t < 128) {                  // tail: units 128..143 (tap 8)
        int e = 1024 + t;
        int u = e >> 3, oct = e & 7;
        int pixl = u & 15;          // k == 8
        int y = h;                  // ky = 2 -> h - 1 + 2
        int xx = w0 + pixl - 1 + 2; // kx = 2
        y = h + 1;
        bool valid = ((unsigned)y < 128u) && ((unsigned)xx < 128u);
        int idx = ((y & 127) << 7) + (xx & 127);
        uint4 v = *(const uint4*)(xtb + ((size_t)idx << 6) + (oct << 3));
        v.x = valid ? v.x : 0u;
        v.y = valid ? v.y : 0u;
        v.z = valid ? v.z : 0u;
        v.w = valid ? v.w : 0u;
        *(uint4*)&S[pixl][8 * 64 + ((oct ^ (pixl & 7)) << 3)] = v;
    }
    __syncthreads();

    // ---- K1: offset/mask conv, waves 0,1 = otile, M=32 x N=16 x K=576 ----
    if (wv < 2) {
        f32x4 k1 = {0.f, 0.f, 0.f, 0.f};
        int brow = lane & 15;
        int hi = lane >> 4;
        int swz = (brow & 7) << 3;
#pragma unroll
        for (int ks = 0; ks < 18; ++ks) {
            short8 a = ((const short8*)OWb)[(wv * 18 + ks) * 64 + lane];
            int coff = ((ks & 1) << 5) + (hi << 3);
            short8 bf = *(const short8*)&S[brow][(ks >> 1) * 64 + (coff ^ swz)];
            k1 = __builtin_amdgcn_mfma_f32_16x16x32_bf16(a, bf, k1, 0, 0, 0);
        }
#pragma unroll
        for (int r = 0; r < 4; ++r) {
            int oc = wv * 16 + (hi << 2) + r;
            if (oc < 18) {
                param[oc][brow] = k1[r] + ob[oc];
            } else if (oc < 27) {
                float s = k1[r] + mb[oc - 18];
                param[oc][brow] = 2.0f / (1.0f + __expf(-s));
            }
        }
    }
    __syncthreads();

    // ---- st1: bilinear corner offsets + weights (threads 0..143) ----
    if (t < 144) {
        int tap = t >> 4, pixl = t & 15;
        int ky = tap / 3, kx = tap - 3 * ky;
        float dy = param[2 * tap][pixl];
        float dx = param[2 * tap + 1][pixl];
        float m  = param[18 + tap][pixl];
        float py = (float)(h - 1 + ky) + dy;
        float px = (float)(w0 + pixl - 1 + kx) + dx;
        float y0f = floorf(py), x0f = floorf(px);
        float fy = py - y0f, fx = px - x0f;
        int y0 = (int)y0f, x0 = (int)x0f;
        int y1 = y0 + 1, x1 = x0 + 1;
        bool vy0 = (unsigned)y0 < (unsigned)H_;
        bool vy1 = (unsigned)y1 < (unsigned)H_;
        bool vx0 = (unsigned)x0 < (unsigned)W_;
        bool vx1 = (unsigned)x1 < (unsigned)W_;
        float w00 = (1.f - fy) * (1.f - fx) * m; if (!(vy0 && vx0)) w00 = 0.f;
        float w01 = (1.f - fy) * fx          * m; if (!(vy0 && vx1)) w01 = 0.f;
        float w10 = fy * (1.f - fx)          * m; if (!(vy1 && vx0)) w10 = 0.f;
        float w11 = fy * fx                   * m; if (!(vy1 && vx1)) w11 = 0.f;
        int y0c = min(max(y0, 0), H_ - 1);
        int y1c = min(max(y1, 0), H_ - 1);
        int x0c = min(max(x0, 0), W_ - 1);
        int x1c = min(max(x1, 0), W_ - 1);
        // byte offsets into xt batch slab: pos (elem) * 64ch * 2B = pos<<7
        pwp[t] = make_int4(((y0c << 7) + x0c) << 7, ((y0c << 7) + x1c) << 7,
                           ((y1c << 7) + x0c) << 7, ((y1c << 7) + x1c) << 7);
        pww[t] = make_ushort4(f2bf(w00), f2bf(w01), f2bf(w10), f2bf(w11));
    }
    __syncthreads();

    // ---- P2: deformable gather, uint2/lane (4ch), 2304 tasks = 9 iters ----
    // unit = tap*16 + pixl, s = 4-ch slot: 16 lanes cover one full 128B
    // corner-row (4 rows per wave-load, full line utilization).
#pragma unroll 3
    for (int i = 0; i < 9; ++i) {
        int e = i * 256 + t;
        int unit = e >> 4, s = e & 15;
        int k = unit >> 4, pixl = unit & 15;
        int4    ofs = pwp[unit];      // broadcast among 16 lanes
        ushort4 wq  = pww[unit];
        float wtx = bf2f(wq.x), wty = bf2f(wq.y);
        float wtz = bf2f(wq.z), wtw = bf2f(wq.w);
        int co = s << 3;              // byte offset within the 128B row
        uint2 r00 = *(const uint2*)(xb8 + ofs.x + co);
        uint2 r01 = *(const uint2*)(xb8 + ofs.y + co);
        uint2 r10 = *(const uint2*)(xb8 + ofs.z + co);
        uint2 r11 = *(const uint2*)(xb8 + ofs.w + co);
        float slo0 = bflo(r00.x) * wtx;
        slo0 = fmaf(bflo(r01.x), wty, slo0);
        slo0 = fmaf(bflo(r10.x), wtz, slo0);
        slo0 = fmaf(bflo(r11.x), wtw, slo0);
        float shi0 = bfhi(r00.x) * wtx;
        shi0 = fmaf(bfhi(r01.x), wty, shi0);
        shi0 = fmaf(bfhi(r10.x), wtz, shi0);
        shi0 = fmaf(bfhi(r11.x), wtw, shi0);
        float slo1 = bflo(r00.y) * wtx;
        slo1 = fmaf(bflo(r01.y), wty, slo1);
        slo1 = fmaf(bflo(r10.y), wtz, slo1);
        slo1 = fmaf(bflo(r11.y), wtw, slo1);
        float shi1 = bfhi(r00.y) * wtx;
        shi1 = fmaf(bfhi(r01.y), wty, shi1);
        shi1 = fmaf(bfhi(r10.y), wtz, shi1);
        shi1 = fmaf(bfhi(r11.y), wtw, shi1);
        uint2 vv;
        vv.x = pkbf(slo0, shi0);
        vv.y = pkbf(slo1, shi1);
        // element map: ch c -> group (c>>3)^(pixl&7), offset c&7
        int col = k * 64 + (((((unsigned)s >> 1) ^ (pixl & 7)) << 3) | ((s & 1) << 2));
        *(uint2*)&S[pixl][col] = vv;
    }
    __syncthreads();

    // ---- P3: main contraction, wave = otile, M=64 x N=16 x K=576 ----
    {
        f32x4 acc = {0.f, 0.f, 0.f, 0.f};
        int brow = lane & 15;
        int hi = lane >> 4;
        int swz = (brow & 7) << 3;
#pragma unroll
        for (int ks = 0; ks < 18; ++ks) {
            int coff = ((ks & 1) << 5) + (hi << 3);
            short8 bfr = *(const short8*)&S[brow][(ks >> 1) * 64 + (coff ^ swz)];
            short8 a = ((const short8*)Wb)[(wv * 18 + ks) * 64 + lane];
            acc = __builtin_amdgcn_mfma_f32_16x16x32_bf16(a, bfr, acc, 0, 0, 0);
        }
        float* op = out + ((size_t)lb << 20) + pix0;
#pragma unroll
        for (int r = 0; r < 4; ++r) {
            int o = wv * 16 + (hi << 2) + r;
            op[((size_t)o << 14) + brow] = acc[r];
        }
    }
}

// -------------------------------------------------------------------------
extern "C" void kernel_launch(void* const* d_in, const int* in_sizes, int n_in,
                              void* d_out, int out_size, void* d_ws, size_t ws_size,
                              hipStream_t stream)
{
    const float* x        = (const float*)d_in[0];
    const float* offset_w = (const float*)d_in[1];
    const float* offset_b = (const float*)d_in[2];
    const float* mod_w    = (const float*)d_in[3];
    const float* mod_b    = (const float*)d_in[4];
    const float* weight   = (const float*)d_in[5];
    float* out = (float*)d_out;

    // Workspace (u16), total ~8.1 MiB:
    //   Wb : 36864 | OWb : 18432 | xt : 4 batches * HW * C = 4,194,304
    u16* Wb  = (u16*)d_ws;
    u16* OWb = Wb + 36864;
    u16* xt  = OWb + 18432;

    prep<<<1240, 256, 0, stream>>>(x, weight, offset_w, mod_w, xt, Wb, OWb);
    fused_dcn<<<4096, 256, 0, stream>>>(xt, Wb, OWb, offset_b, mod_b, out);
}

// Round 14
// 43.993 us; speedup vs baseline: 1.7409x; 1.1747x over previous
//
#include <hip/hip_runtime.h>
#include <hip/hip_bf16.h>
#include <math.h>

typedef unsigned short u16;
typedef unsigned int   u32;
typedef __attribute__((ext_vector_type(8))) short short8;
typedef __attribute__((ext_vector_type(4))) float f32x4;

// Problem constants
#define B_  4
#define C_  64
#define H_  128
#define W_  128
#define O_  64
#define HW_ (H_ * W_)

__device__ __forceinline__ u16 f2bf(float f) {
    __hip_bfloat16 h = __float2bfloat16(f);
    u16 u; __builtin_memcpy(&u, &h, 2); return u;
}
__device__ __forceinline__ float bf2f(u16 u) {
    return __uint_as_float((u32)u << 16);
}
__device__ __forceinline__ u32 pkbf(float lo, float hi) {
    return ((u32)f2bf(hi) << 16) | (u32)f2bf(lo);
}
__device__ __forceinline__ float bflo(u32 v) { return __uint_as_float(v << 16); }
__device__ __forceinline__ float bfhi(u32 v) { return __uint_as_float(v & 0xffff0000u); }

// interp 8 channels (one uint4 = 8 bf16 per corner) -> packed uint4
__device__ __forceinline__ uint4 interp8(
    uint4 c00, uint4 c01, uint4 c10, uint4 c11,
    float wtx, float wty, float wtz, float wtw)
{
    const u32* q00 = (const u32*)&c00;
    const u32* q01 = (const u32*)&c01;
    const u32* q10 = (const u32*)&c10;
    const u32* q11 = (const u32*)&c11;
    u32 bw[4];
#pragma unroll
    for (int q = 0; q < 4; ++q) {
        float slo = bflo(q00[q]) * wtx;
        slo = fmaf(bflo(q01[q]), wty, slo);
        slo = fmaf(bflo(q10[q]), wtz, slo);
        slo = fmaf(bflo(q11[q]), wtw, slo);
        float shi = bfhi(q00[q]) * wtx;
        shi = fmaf(bfhi(q01[q]), wty, shi);
        shi = fmaf(bfhi(q10[q]), wtz, shi);
        shi = fmaf(bfhi(q11[q]), wtw, shi);
        bw[q] = pkbf(slo, shi);
    }
    uint4 v; __builtin_memcpy(&v, bw, 16);
    return v;
}

// -------------------------------------------------------------------------
// prep: blocks 0..1023   : transpose x (B,C,H,W) f32 -> xt (B,H,W,C) bf16
//       blocks 1024..1239: repack weight->Wb, ow|mw->OWb (A-frag order)
// K index convention: kidx = tap*64 + c  (tap-major, channel minor)
// A-frag (16x16x32): lane l holds A[o = l&15][k = ks*32 + (l>>4)*8 + j]
// -------------------------------------------------------------------------
__global__ __launch_bounds__(256) void prep(
    const float* __restrict__ x, const float* __restrict__ weight,
    const float* __restrict__ ow, const float* __restrict__ mw,
    u16* __restrict__ xt, u16* __restrict__ Wb, u16* __restrict__ OWb)
{
    int i = blockIdx.x, t = threadIdx.x;
    if (i < 1024) {                             // transpose
        __shared__ float tile[64][65];
        int lb = i >> 8;                        // 0..3
        int pix0 = (i & 255) << 6;
        const float* xb = x + ((size_t)lb << 20);
#pragma unroll
        for (int it = 0; it < 16; ++it) {
            int e = it * 256 + t;
            int c = e >> 6, pl = e & 63;
            tile[c][pl] = xb[((size_t)c << 14) + pix0 + pl];
        }
        __syncthreads();
        u16* xo = xt + ((((size_t)lb << 14) + pix0) << 6);
#pragma unroll
        for (int it = 0; it < 16; ++it) {
            int e = it * 256 + t;
            int c = e & 63, pl = e >> 6;
            xo[((size_t)pl << 6) + c] = f2bf(tile[c][pl]);
        }
    } else {
        int e = (i - 1024) * 256 + t;           // 0..55295
        if (e < 36864) {                        // Wb
            int j = e & 7, ln = (e >> 3) & 63;
            int ks = (e >> 9) % 18, ot = e / 9216;
            int o = ot * 16 + (ln & 15);
            int kidx = ks * 32 + ((ln >> 4) << 3) + j;
            int k = kidx >> 6, c = kidx & 63;
            Wb[e] = f2bf(weight[((size_t)(o * 64 + c)) * 9 + k]);
        } else {                                // OWb
            int e2 = e - 36864;
            int j = e2 & 7, ln = (e2 >> 3) & 63;
            int ks = (e2 >> 9) % 18, ot = e2 / 9216;
            int o = ot * 16 + (ln & 15);
            int kidx = ks * 32 + ((ln >> 4) << 3) + j;
            int k = kidx >> 6, c = kidx & 63;
            float v = 0.0f;
            if (o < 18)      v = ow[((size_t)(o * 64 + c)) * 9 + k];
            else if (o < 27) v = mw[((size_t)((o - 18) * 64 + c)) * 9 + k];
            OWb[e2] = f2bf(v);
        }
    }
}

// -------------------------------------------------------------------------
// fused_dcn: r13 structure with P2 widened to uint4/lane and explicitly
// 2-task batched (8 x 16B corner loads pinned in flight via sched_barrier).
// Block = 16 pixels (one row segment), 4 waves, 4 barriers:
//   P0 : im2col staging, uint4/lane, oct-fastest -> S swizzled
//   K1 : waves 0,1 (= otile): 18 swizzled ds_read_b128 + 18 MFMA -> param
//   st1: threads 0..143: bilinear corner byte-offsets (int4) + bf16 wts
//   P2 : deformable gather, uint4/lane (8ch), oct-fastest (8 lanes cover a
//        full 128B corner-row), 2-task batches -> rebuild S swizzled
//   P3 : wave = otile: 18 swizzled ds_read_b128 + A-frags + MFMA -> out
// LDS: 18432 + 1728 + 2304 + 1152 = 23616 B -> 6 blocks/CU.
// launch_bounds(256,6) caps VGPR ~85 -> occupancy stays 24 waves/CU.
// -------------------------------------------------------------------------
__global__ __launch_bounds__(256, 6) void fused_dcn(
    const u16* __restrict__ xt,
    const u16* __restrict__ Wb, const u16* __restrict__ OWb,
    const float* __restrict__ ob, const float* __restrict__ mb,
    float* __restrict__ out)
{
    __shared__ __align__(16) u16 S[16][576];     // 18432 B, group-XOR swizzled
    __shared__ float   param[27][16];            //  1728 B
    __shared__ __align__(16) int4    pwp[144];   //  2304 B corner byte offsets
    __shared__ __align__(16) ushort4 pww[144];   //  1152 B bf16 bilinear*mask wts

    const int t = threadIdx.x;
    const int lane = t & 63;
    const int wv = t >> 6;          // 0..3

    int bid0 = blockIdx.x;          // 4096 blocks
    const int bid = (bid0 & 7) * 512 + (bid0 >> 3);   // XCD swizzle (bijective)
    const int lb = bid >> 10;       // batch
    const int pix0 = (bid & 1023) << 4;
    const int h  = pix0 >> 7;       // 16 pixels share one row
    const int w0 = pix0 & 127;

    const u16* xtb = xt + ((size_t)lb << 20);
    const char* xb8 = (const char*)xtb;

    // ---- P0: im2col staging, uint4/lane, 1152 tasks (144 units x 8 octs) ----
#pragma unroll
    for (int i = 0; i < 4; ++i) {
        int e = i * 256 + t;
        int u = e >> 3, oct = e & 7;
        int k = u >> 4, pixl = u & 15;
        int ky = k / 3, kx = k - 3 * ky;
        int y = h - 1 + ky, xx = w0 + pixl - 1 + kx;
        bool valid = ((unsigned)y < 128u) && ((unsigned)xx < 128u);
        int idx = ((y & 127) << 7) + (xx & 127);
        uint4 v = *(const uint4*)(xtb + ((size_t)idx << 6) + (oct << 3));
        v.x = valid ? v.x : 0u;
        v.y = valid ? v.y : 0u;
        v.z = valid ? v.z : 0u;
        v.w = valid ? v.w : 0u;
        *(uint4*)&S[pixl][k * 64 + ((oct ^ (pixl & 7)) << 3)] = v;
    }
    if (t < 128) {                  // tail: units 128..143 (tap 8)
        int e = 1024 + t;
        int u = e >> 3, oct = e & 7;
        int pixl = u & 15;          // k == 8 -> ky=2, kx=2
        int y = h + 1;
        int xx = w0 + pixl - 1 + 2;
        bool valid = ((unsigned)y < 128u) && ((unsigned)xx < 128u);
        int idx = ((y & 127) << 7) + (xx & 127);
        uint4 v = *(const uint4*)(xtb + ((size_t)idx << 6) + (oct << 3));
        v.x = valid ? v.x : 0u;
        v.y = valid ? v.y : 0u;
        v.z = valid ? v.z : 0u;
        v.w = valid ? v.w : 0u;
        *(uint4*)&S[pixl][8 * 64 + ((oct ^ (pixl & 7)) << 3)] = v;
    }
    __syncthreads();

    // ---- K1: offset/mask conv, waves 0,1 = otile, M=32 x N=16 x K=576 ----
    if (wv < 2) {
        f32x4 k1 = {0.f, 0.f, 0.f, 0.f};
        int brow = lane & 15;
        int hi = lane >> 4;
        int swz = (brow & 7) << 3;
#pragma unroll
        for (int ks = 0; ks < 18; ++ks) {
            short8 a = ((const short8*)OWb)[(wv * 18 + ks) * 64 + lane];
            int coff = ((ks & 1) << 5) + (hi << 3);
            short8 bf = *(const short8*)&S[brow][(ks >> 1) * 64 + (coff ^ swz)];
            k1 = __builtin_amdgcn_mfma_f32_16x16x32_bf16(a, bf, k1, 0, 0, 0);
        }
#pragma unroll
        for (int r = 0; r < 4; ++r) {
            int oc = wv * 16 + (hi << 2) + r;
            if (oc < 18) {
                param[oc][brow] = k1[r] + ob[oc];
            } else if (oc < 27) {
                float s = k1[r] + mb[oc - 18];
                param[oc][brow] = 2.0f / (1.0f + __expf(-s));
            }
        }
    }
    __syncthreads();

    // ---- st1: bilinear corner offsets + weights (threads 0..143) ----
    if (t < 144) {
        int tap = t >> 4, pixl = t & 15;
        int ky = tap / 3, kx = tap - 3 * ky;
        float dy = param[2 * tap][pixl];
        float dx = param[2 * tap + 1][pixl];
        float m  = param[18 + tap][pixl];
        float py = (float)(h - 1 + ky) + dy;
        float px = (float)(w0 + pixl - 1 + kx) + dx;
        float y0f = floorf(py), x0f = floorf(px);
        float fy = py - y0f, fx = px - x0f;
        int y0 = (int)y0f, x0 = (int)x0f;
        int y1 = y0 + 1, x1 = x0 + 1;
        bool vy0 = (unsigned)y0 < (unsigned)H_;
        bool vy1 = (unsigned)y1 < (unsigned)H_;
        bool vx0 = (unsigned)x0 < (unsigned)W_;
        bool vx1 = (unsigned)x1 < (unsigned)W_;
        float w00 = (1.f - fy) * (1.f - fx) * m; if (!(vy0 && vx0)) w00 = 0.f;
        float w01 = (1.f - fy) * fx          * m; if (!(vy0 && vx1)) w01 = 0.f;
        float w10 = fy * (1.f - fx)          * m; if (!(vy1 && vx0)) w10 = 0.f;
        float w11 = fy * fx                   * m; if (!(vy1 && vx1)) w11 = 0.f;
        int y0c = min(max(y0, 0), H_ - 1);
        int y1c = min(max(y1, 0), H_ - 1);
        int x0c = min(max(x0, 0), W_ - 1);
        int x1c = min(max(x1, 0), W_ - 1);
        // byte offsets into xt batch slab: pos (elem) * 64ch * 2B = pos<<7
        pwp[t] = make_int4(((y0c << 7) + x0c) << 7, ((y0c << 7) + x1c) << 7,
                           ((y1c << 7) + x0c) << 7, ((y1c << 7) + x1c) << 7);
        pww[t] = make_ushort4(f2bf(w00), f2bf(w01), f2bf(w10), f2bf(w11));
    }
    __syncthreads();

    // ---- P2: deformable gather, uint4/lane (8ch), 1152 tasks, 2-task batch ----
    // unit = tap*16 + pixl, oct = channel octet: 8 lanes cover one full
    // 128B corner-row. Both tasks' 8 corner loads issued before any interp
    // (sched_barrier pins them) -> 8 x 16B outstanding per wave.
#pragma unroll
    for (int ii = 0; ii < 2; ++ii) {
        int e0 = ii * 512 + t;
        int e1 = e0 + 256;
        int u0 = e0 >> 3, o0 = e0 & 7;
        int u1 = e1 >> 3, o1 = e1 & 7;
        int4    ofs0 = pwp[u0]; ushort4 wq0 = pww[u0];
        int4    ofs1 = pwp[u1]; ushort4 wq1 = pww[u1];
        uint4 a00 = *(const uint4*)(xb8 + ofs0.x + (o0 << 4));
        uint4 a01 = *(const uint4*)(xb8 + ofs0.y + (o0 << 4));
        uint4 a10 = *(const uint4*)(xb8 + ofs0.z + (o0 << 4));
        uint4 a11 = *(const uint4*)(xb8 + ofs0.w + (o0 << 4));
        uint4 b00 = *(const uint4*)(xb8 + ofs1.x + (o1 << 4));
        uint4 b01 = *(const uint4*)(xb8 + ofs1.y + (o1 << 4));
        uint4 b10 = *(const uint4*)(xb8 + ofs1.z + (o1 << 4));
        uint4 b11 = *(const uint4*)(xb8 + ofs1.w + (o1 << 4));
        __builtin_amdgcn_sched_barrier(0);
        {
            int k = u0 >> 4, pixl = u0 & 15;
            uint4 v = interp8(a00, a01, a10, a11,
                              bf2f(wq0.x), bf2f(wq0.y), bf2f(wq0.z), bf2f(wq0.w));
            *(uint4*)&S[pixl][k * 64 + ((o0 ^ (pixl & 7)) << 3)] = v;
        }
        {
            int k = u1 >> 4, pixl = u1 & 15;
            uint4 v = interp8(b00, b01, b10, b11,
                              bf2f(wq1.x), bf2f(wq1.y), bf2f(wq1.z), bf2f(wq1.w));
            *(uint4*)&S[pixl][k * 64 + ((o1 ^ (pixl & 7)) << 3)] = v;
        }
    }
    if (t < 128) {                  // tail: units 128..143 (tap 8)
        int e = 1024 + t;
        int u = e >> 3, oct = e & 7;
        int pixl = u & 15;
        int4    ofs = pwp[u]; ushort4 wq = pww[u];
        uint4 c00 = *(const uint4*)(xb8 + ofs.x + (oct << 4));
        uint4 c01 = *(const uint4*)(xb8 + ofs.y + (oct << 4));
        uint4 c10 = *(const uint4*)(xb8 + ofs.z + (oct << 4));
        uint4 c11 = *(const uint4*)(xb8 + ofs.w + (oct << 4));
        uint4 v = interp8(c00, c01, c10, c11,
                          bf2f(wq.x), bf2f(wq.y), bf2f(wq.z), bf2f(wq.w));
        *(uint4*)&S[pixl][8 * 64 + ((oct ^ (pixl & 7)) << 3)] = v;
    }
    __syncthreads();

    // ---- P3: main contraction, wave = otile, M=64 x N=16 x K=576 ----
    {
        f32x4 acc = {0.f, 0.f, 0.f, 0.f};
        int brow = lane & 15;
        int hi = lane >> 4;
        int swz = (brow & 7) << 3;
#pragma unroll
        for (int ks = 0; ks < 18; ++ks) {
            int coff = ((ks & 1) << 5) + (hi << 3);
            short8 bfr = *(const short8*)&S[brow][(ks >> 1) * 64 + (coff ^ swz)];
            short8 a = ((const short8*)Wb)[(wv * 18 + ks) * 64 + lane];
            acc = __builtin_amdgcn_mfma_f32_16x16x32_bf16(a, bfr, acc, 0, 0, 0);
        }
        float* op = out + ((size_t)lb << 20) + pix0;
#pragma unroll
        for (int r = 0; r < 4; ++r) {
            int o = wv * 16 + (hi << 2) + r;
            op[((size_t)o << 14) + brow] = acc[r];
        }
    }
}

// -------------------------------------------------------------------------
extern "C" void kernel_launch(void* const* d_in, const int* in_sizes, int n_in,
                              void* d_out, int out_size, void* d_ws, size_t ws_size,
                              hipStream_t stream)
{
    const float* x        = (const float*)d_in[0];
    const float* offset_w = (const float*)d_in[1];
    const float* offset_b = (const float*)d_in[2];
    const float* mod_w    = (const float*)d_in[3];
    const float* mod_b    = (const float*)d_in[4];
    const float* weight   = (const float*)d_in[5];
    float* out = (float*)d_out;

    // Workspace (u16), total ~8.1 MiB:
    //   Wb : 36864 | OWb : 18432 | xt : 4 batches * HW * C = 4,194,304
    u16* Wb  = (u16*)d_ws;
    u16* OWb = Wb + 36864;
    u16* xt  = OWb + 18432;

    prep<<<1240, 256, 0, stream>>>(x, weight, offset_w, mod_w, xt, Wb, OWb);
    fused_dcn<<<4096, 256, 0, stream>>>(xt, Wb, OWb, offset_b, mod_b, out);
}